// Round 11
// baseline (828.187 us; speedup 1.0000x reference)
//
#include <hip/hip_runtime.h>
#include <cmath>

// Problem constants (B,N,DIM,HEADS)=(4,4096,1024,16), SX=SY=2, ratio .9
#define B_  4
#define N_  4096
#define C_  1024
#define H_  16
#define D_  64
#define ND_ 1024   // num dst tokens (one per 2x2 block)
#define NA_ 3072   // num src (a) tokens
// r = min(3072, int(4096*0.9)) = 3072  => unm empty, sort permutation cancels.

typedef __attribute__((ext_vector_type(8))) short short8v;
typedef __attribute__((ext_vector_type(4))) float f32x4;

// ---------------------------------------------------------------------------
// threefry2x32 (20 rounds), returns BOTH output words.
// ---------------------------------------------------------------------------
__device__ inline void tf2x32(unsigned k0, unsigned k1, unsigned x0, unsigned x1,
                              unsigned& o0, unsigned& o1) {
  const unsigned ks2 = 0x1BD11BDAu ^ k0 ^ k1;
  x0 += k0; x1 += k1;
#define RND_(r) { x0 += x1; x1 = (x1 << (r)) | (x1 >> (32 - (r))); x1 ^= x0; }
  RND_(13) RND_(15) RND_(26) RND_(6)
  x0 += k1;  x1 += ks2 + 1u;
  RND_(17) RND_(29) RND_(16) RND_(24)
  x0 += ks2; x1 += k0 + 2u;
  RND_(13) RND_(15) RND_(26) RND_(6)
  x0 += k0;  x1 += k1 + 3u;
  RND_(17) RND_(29) RND_(16) RND_(24)
  x0 += k1;  x1 += ks2 + 4u;
  RND_(13) RND_(15) RND_(26) RND_(6)
  x0 += ks2; x1 += k0 + 5u;
#undef RND_
  o0 = x0; o1 = x1;
}

// ---------------------------------------------------------------------------
// K1 (VERIFIED r7): jax.random.randint(key(33),(32,32),0,4)
// ---------------------------------------------------------------------------
__global__ __launch_bounds__(1024) void k_init_indices(int* __restrict__ b_idx,
                                                       int* __restrict__ a_idx) {
  __shared__ unsigned char randk[1024];
  __shared__ int wtot[16], wpre[16];
  const int tid = threadIdx.x;
  {
    unsigned c0, c1;
    tf2x32(0u, 33u, 0u, 1u, c0, c1);                 // k2 = split(key)[1]
    unsigned d0, d1;
    tf2x32(c0, c1, 0u, (unsigned)tid, d0, d1);       // random_bits element p
    randk[tid] = (unsigned char)((d0 ^ d1) & 3u);    // xor-fold, % span
  }
  __syncthreads();
  const int base_t = tid * 4;
  int f[4]; int cnt = 0;
#pragma unroll
  for (int j = 0; j < 4; j++) {
    const int t = base_t + j;
    const int y = t >> 6, xc = t & 63;
    const int bi = (y >> 1) * 32 + (xc >> 1);
    const int k  = (y & 1) * 2 + (xc & 1);
    f[j] = (randk[bi] == (unsigned char)k) ? 1 : 0;
    cnt += f[j];
  }
  const int lane = tid & 63, wave = tid >> 6;
  int incl = cnt;
#pragma unroll
  for (int off = 1; off < 64; off <<= 1) {
    int nb = __shfl_up(incl, off, 64);
    if (lane >= off) incl += nb;
  }
  if (lane == 63) wtot[wave] = incl;
  __syncthreads();
  if (tid == 0) { int s = 0; for (int w = 0; w < 16; w++) { wpre[w] = s; s += wtot[w]; } }
  __syncthreads();
  int P = wpre[wave] + (incl - cnt);   // #dst strictly before base_t
#pragma unroll
  for (int j = 0; j < 4; j++) {
    const int t = base_t + j;
    if (f[j]) { b_idx[P] = t; P++; }
    else      { a_idx[t - P] = t; }
  }
}

// ---------------------------------------------------------------------------
// K2: per-token inverse L2 norm of x, fp64
// ---------------------------------------------------------------------------
__global__ __launch_bounds__(256) void k_row_norms(const float* __restrict__ x,
                                                   double* __restrict__ dinv) {
  const int row = blockIdx.x;                 // B_*N_
  const float* xr = x + (size_t)row * C_;
  const int tid = threadIdx.x;
  float4 v = ((const float4*)xr)[tid];
  double s = (double)v.x * (double)v.x + (double)v.y * (double)v.y +
             (double)v.z * (double)v.z + (double)v.w * (double)v.w;
#pragma unroll
  for (int off = 32; off; off >>= 1) s += __shfl_down(s, off, 64);
  __shared__ double wsum[4];
  if ((tid & 63) == 0) wsum[tid >> 6] = s;
  __syncthreads();
  if (tid == 0) {
    double t = wsum[0] + wsum[1] + wsum[2] + wsum[3];
    dinv[row] = 1.0 / sqrt(t);
  }
}

// ---------------------------------------------------------------------------
// bf16 split helpers (RTNE)
// ---------------------------------------------------------------------------
__device__ inline unsigned short f2bf_rtne(float f) {
  const unsigned u = __float_as_uint(f);
  return (unsigned short)((u + 0x7FFFu + ((u >> 16) & 1u)) >> 16);
}

__device__ inline void split8(const float* f, short8v& h8, short8v& l8) {
#pragma unroll
  for (int j = 0; j < 8; j++) {
    const unsigned short hv = f2bf_rtne(f[j]);
    const float fh = __uint_as_float((unsigned)hv << 16);
    const unsigned short lv = f2bf_rtne(f[j] - fh);
    h8[j] = (short)hv; l8[j] = (short)lv;
  }
}

// ---------------------------------------------------------------------------
// K2b: normalized rows split into bf16 hi + bf16 lo (RTNE), for MFMA scores.
// ---------------------------------------------------------------------------
__global__ __launch_bounds__(256) void k_prep(const float* __restrict__ x,
                                              const double* __restrict__ dinv,
                                              unsigned short* __restrict__ xh,
                                              unsigned short* __restrict__ xl) {
  const int row = blockIdx.x;                 // B_*N_
  const float ia = (float)dinv[row];
  const float4 v = ((const float4*)(x + (size_t)row * C_))[threadIdx.x];
  float f[4] = {v.x * ia, v.y * ia, v.z * ia, v.w * ia};
  unsigned h[4], l[4];
#pragma unroll
  for (int j = 0; j < 4; j++) {
    h[j] = f2bf_rtne(f[j]);
    const float fh = __uint_as_float(h[j] << 16);
    l[j] = f2bf_rtne(f[j] - fh);
  }
  const size_t o = (size_t)row * C_ + threadIdx.x * 4;
  uint2 ph, pl;
  ph.x = h[0] | (h[1] << 16); ph.y = h[2] | (h[3] << 16);
  pl.x = l[0] | (l[1] << 16); pl.y = l[2] | (l[3] << 16);
  *(uint2*)&xh[o] = ph;
  *(uint2*)&xl[o] = pl;
}

// ---------------------------------------------------------------------------
// K2c: split Wqkv (3072x1024) and Wp (1024x1024) into bf16 hi/lo.
// ---------------------------------------------------------------------------
__global__ __launch_bounds__(256) void k_prep_w(const float* __restrict__ Wqkv,
                                                const float* __restrict__ Wp,
                                                unsigned short* __restrict__ wqh,
                                                unsigned short* __restrict__ wql,
                                                unsigned short* __restrict__ wph,
                                                unsigned short* __restrict__ wpl) {
  const int row = blockIdx.x;            // 0..4095
  const float* src;
  unsigned short *dh, *dl;
  size_t o;
  if (row < 3072) { src = Wqkv + (size_t)row * C_; dh = wqh; dl = wql; o = (size_t)row * C_; }
  else { src = Wp + (size_t)(row - 3072) * C_; dh = wph; dl = wpl; o = (size_t)(row - 3072) * C_; }
  const float4 v = ((const float4*)src)[threadIdx.x];
  const float f[4] = {v.x, v.y, v.z, v.w};
  unsigned h4[4], l4[4];
#pragma unroll
  for (int j = 0; j < 4; j++) {
    h4[j] = f2bf_rtne(f[j]);
    const float fh = __uint_as_float(h4[j] << 16);
    l4[j] = f2bf_rtne(f[j] - fh);
  }
  uint2 ph, pl;
  ph.x = h4[0] | (h4[1] << 16); ph.y = h4[2] | (h4[3] << 16);
  pl.x = l4[0] | (l4[1] << 16); pl.y = l4[2] | (l4[3] << 16);
  *(uint2*)&dh[o + threadIdx.x * 4] = ph;
  *(uint2*)&dl[o + threadIdx.x * 4] = pl;
}

// top-2 merge tracking both indices
__device__ inline void top2m(float& v1, int& i1, float& v2, int& i2,
                             float ov1, int oi1, float ov2, int oi2) {
  if (ov1 > v1 || (ov1 == v1 && oi1 < i1)) {
    if (v1 > ov2 || (v1 == ov2 && i1 < oi2)) { v2 = v1; i2 = i1; }
    else { v2 = ov2; i2 = oi2; }
    v1 = ov1; i1 = oi1;
  } else if (ov1 > v2 || (ov1 == v2 && oi1 < i2)) {
    v2 = ov1; i2 = oi1;
  }
}

// ---------------------------------------------------------------------------
// K3: scores via bf16x3 MFMA, 128x128 tile, BK=32, BARRIER-FREE direct-L2:
// fragment gather pattern (row idx[..+fr], cols k0+fg*8) is per-lane, so
// global b128 loads feed MFMA directly -- no LDS staging, no __syncthreads
// in the K-loop. Same data volume, same MFMA order (bitwise-identical acc).
// ---------------------------------------------------------------------------
__global__ __launch_bounds__(256) void k_scores_mfma(
    const unsigned short* __restrict__ xh, const unsigned short* __restrict__ xl,
    const int* __restrict__ a_idx, const int* __restrict__ b_idx,
    float* __restrict__ pv1, int* __restrict__ pi1,
    float* __restrict__ pv2, int* __restrict__ pi2) {
  __shared__ float mv1[128][2], mv2[128][2];
  __shared__ int   mi1[128][2], mi2[128][2];
  const int bz = blockIdx.z, cb = blockIdx.x, sb = blockIdx.y;  // cb: 8, sb: 24
  const int tid = threadIdx.x;
  const int lane = tid & 63, wv = tid >> 6;
  const int wr = wv >> 1, wc = wv & 1;
  const int fr = lane & 15, fg = lane >> 4;
  // per-lane row bases (element offsets), + fg*8 column base
  size_t aoff[4], boff[4];
#pragma unroll
  for (int i = 0; i < 4; i++) {
    aoff[i] = ((size_t)bz * N_ + a_idx[sb * 128 + wr * 64 + i * 16 + fr]) * C_ + fg * 8;
    boff[i] = ((size_t)bz * N_ + b_idx[cb * 128 + wc * 64 + i * 16 + fr]) * C_ + fg * 8;
  }
  f32x4 acc[4][4] = {};
  for (int k0 = 0; k0 < C_; k0 += 32) {
    short8v bh[4], bl[4];
#pragma unroll
    for (int j = 0; j < 4; j++) {
      bh[j] = *(const short8v*)(xh + boff[j] + k0);
      bl[j] = *(const short8v*)(xl + boff[j] + k0);
    }
#pragma unroll
    for (int i = 0; i < 4; i++) {
      const short8v ah = *(const short8v*)(xh + aoff[i] + k0);
      const short8v al = *(const short8v*)(xl + aoff[i] + k0);
#pragma unroll
      for (int j = 0; j < 4; j++) {
        acc[i][j] = __builtin_amdgcn_mfma_f32_16x16x32_bf16(al, bh[j], acc[i][j], 0, 0, 0);
        acc[i][j] = __builtin_amdgcn_mfma_f32_16x16x32_bf16(ah, bl[j], acc[i][j], 0, 0, 0);
        acc[i][j] = __builtin_amdgcn_mfma_f32_16x16x32_bf16(ah, bh[j], acc[i][j], 0, 0, 0);
      }
    }
  }
  // top-2 epilogue. D layout: col = fr (within 16), row = fg*4 + r (m89).
#pragma unroll
  for (int i = 0; i < 4; i++) {
#pragma unroll
    for (int r = 0; r < 4; r++) {
      float v1 = acc[i][0][r]; int i1 = cb * 128 + wc * 64 + fr;
      float v2 = -INFINITY;    int i2 = i1;
#pragma unroll
      for (int j = 1; j < 4; j++) {
        const float v = acc[i][j][r];
        const int d = cb * 128 + wc * 64 + j * 16 + fr;
        if (v > v1) { v2 = v1; i2 = i1; v1 = v; i1 = d; }
        else if (v > v2) { v2 = v; i2 = d; }
      }
#pragma unroll
      for (int off = 8; off; off >>= 1) {
        const float ov1 = __shfl_xor(v1, off, 16);
        const int   oi1 = __shfl_xor(i1, off, 16);
        const float ov2 = __shfl_xor(v2, off, 16);
        const int   oi2 = __shfl_xor(i2, off, 16);
        top2m(v1, i1, v2, i2, ov1, oi1, ov2, oi2);
      }
      if (fr == 0) {
        const int rl = wr * 64 + i * 16 + fg * 4 + r;
        mv1[rl][wc] = v1; mi1[rl][wc] = i1; mv2[rl][wc] = v2; mi2[rl][wc] = i2;
      }
    }
  }
  __syncthreads();
  if (tid < 128) {
    float v1 = mv1[tid][0], v2 = mv2[tid][0];
    int   i1 = mi1[tid][0], i2 = mi2[tid][0];
    top2m(v1, i1, v2, i2, mv1[tid][1], mi1[tid][1], mv2[tid][1], mi2[tid][1]);
    const int s = sb * 128 + tid;
    const size_t o = ((size_t)bz * NA_ + s) * 8 + cb;
    pv1[o] = v1; pi1[o] = i1; pv2[o] = v2; pi2[o] = i2;
  }
}

// K4: merge 8 per-tile partials -> node_idx; append near-ties to flaglist.
// eps(bf16x3) <= ~1e-5; 2*eps ~= 2e-5. Flag at 1e-4 (5x margin): unflagged =>
// gap > 1e-4 > 2*eps => argmax exact.
__global__ __launch_bounds__(256) void k_finalize(
    const float* __restrict__ pv1, const int* __restrict__ pi1,
    const float* __restrict__ pv2, const int* __restrict__ pi2,
    int* __restrict__ node_idx, int* __restrict__ flaglist,
    int* __restrict__ nflag) {
  const int r = blockIdx.x * 256 + threadIdx.x;   // [0, B_*NA_)
  if (r >= B_ * NA_) return;
  size_t o = (size_t)r * 8;
  float v1 = pv1[o]; int i1 = pi1[o]; float v2 = pv2[o]; int i2 = pi2[o];
  for (int cb = 1; cb < 8; cb++)
    top2m(v1, i1, v2, i2, pv1[o + cb], pi1[o + cb], pv2[o + cb], pi2[o + cb]);
  node_idx[r] = i1;
  if (v1 - v2 < 1e-4f) flaglist[atomicAdd(nflag, 1)] = r;
}

// ---------------------------------------------------------------------------
// K5: fp64 recheck over COMPACTED flag list, persistent blocks.
// Candidate/scan threshold 5e-5; nc==1 early-out; 4-way ILP batches.
// ---------------------------------------------------------------------------
__global__ __launch_bounds__(256) void k_recheck(
    const float* __restrict__ x, const double* __restrict__ dinv,
    const int* __restrict__ a_idx, const int* __restrict__ b_idx,
    const float* __restrict__ pv1, const int* __restrict__ pi1,
    const float* __restrict__ pv2, const int* __restrict__ pi2,
    const int* __restrict__ flaglist, const int* __restrict__ nflag,
    int* __restrict__ node_idx) {
  __shared__ double arow[C_];
  __shared__ int cand[1088];
  __shared__ int ncand;
  __shared__ float v1s[8];
  __shared__ double bvs[4]; __shared__ int bis[4];
  const int tid = threadIdx.x;
  const int lane = tid & 63, wave = tid >> 6;
  const int nf = *nflag;
  for (int it = blockIdx.x; it < nf; it += gridDim.x) {
    const int r = flaglist[it];                 // bz*NA_ + s
    const int bz = r / NA_, s = r % NA_;
    const size_t o = (size_t)r * 8;
    if (tid < 8) v1s[tid] = pv1[o + tid];
    if (tid == 0) ncand = 0;
    __syncthreads();
    float v1g = v1s[0];
#pragma unroll
    for (int cb = 1; cb < 8; cb++) v1g = fmaxf(v1g, v1s[cb]);
    if (tid < 8) {
      const float tv1 = pv1[o + tid], tv2 = pv2[o + tid];
      if (tv2 >= v1g - 5e-5f) {
        // tile may hide more near-max entries -> scan whole 128-dst tile
        const int base = atomicAdd(&ncand, 128);
        for (int j = 0; j < 128; j++) cand[base + j] = tid * 128 + j;
      } else if (tv1 >= v1g - 5e-5f) {
        cand[atomicAdd(&ncand, 1)] = pi1[o + tid];
      }
    }
    __syncthreads();
    const int nc = ncand;
    if (nc == 1) { __syncthreads(); continue; }   // unique candidate = node_idx
    // stage a-row in fp64 (only when actually needed)
    const int ga = a_idx[s];
    const double ia = dinv[bz * N_ + ga];
    const float* xa = x + ((size_t)bz * N_ + ga) * C_;
    for (int c = tid; c < C_; c += 256) arow[c] = (double)xa[c] * ia;
    __syncthreads();
    double bv = -1e300; int bi = 1 << 30;
    for (int cb0 = wave * 4; cb0 < nc; cb0 += 16) {   // 4 candidates per wave batch
      double sum[4] = {0.0, 0.0, 0.0, 0.0};
      int dd[4]; const float* xb[4]; double ibv[4]; bool val[4];
#pragma unroll
      for (int u = 0; u < 4; u++) {
        const int ci = cb0 + u;
        val[u] = (ci < nc);
        const int dv = cand[val[u] ? ci : 0];
        dd[u] = dv;
        const int gb = b_idx[dv];
        ibv[u] = dinv[bz * N_ + gb];
        xb[u] = x + ((size_t)bz * N_ + gb) * C_;
      }
      for (int c = lane; c < C_; c += 64) {
        const double a = arow[c];
#pragma unroll
        for (int u = 0; u < 4; u++) sum[u] += a * ((double)xb[u][c] * ibv[u]);
      }
#pragma unroll
      for (int u = 0; u < 4; u++) {
#pragma unroll
        for (int off = 32; off; off >>= 1) sum[u] += __shfl_xor(sum[u], off, 64);
        if (val[u] && (sum[u] > bv || (sum[u] == bv && dd[u] < bi))) { bv = sum[u]; bi = dd[u]; }
      }
    }
    if (lane == 0) { bvs[wave] = bv; bis[wave] = bi; }
    __syncthreads();
    if (tid == 0) {
      for (int w = 1; w < 4; w++)
        if (bvs[w] > bv || (bvs[w] == bv && bis[w] < bi)) { bv = bvs[w]; bi = bis[w]; }
      node_idx[r] = bi;
    }
    __syncthreads();
  }
}

// K6: token->merged-row map (cnt no longer needed; fused merge counts itself)
__global__ __launch_bounds__(256) void k_rowmap(
    const int* __restrict__ a_idx, const int* __restrict__ b_idx,
    const int* __restrict__ node_idx, int* __restrict__ rowmap) {
  const int i = blockIdx.x * 256 + threadIdx.x;   // [0, B_*N_)
  if (i >= B_ * N_) return;
  const int bz = i >> 12, j = i & 4095;
  if (j < NA_) {
    rowmap[bz * N_ + a_idx[j]] = node_idx[bz * NA_ + j];
  } else {
    const int d = j - NA_;
    rowmap[bz * N_ + b_idx[d]] = d;
  }
}

// ---------------------------------------------------------------------------
// K7 (fused merge): one block per (bz,dst). Scan node_idx for sources via
// ballot-compaction (deterministic ascending order), sum rows, scale, emit
// bf16 hi/lo directly.
// ---------------------------------------------------------------------------
__global__ __launch_bounds__(256) void k_merge_fused(
    const float* __restrict__ x, const int* __restrict__ a_idx,
    const int* __restrict__ b_idx, const int* __restrict__ node_idx,
    unsigned short* __restrict__ xmh, unsigned short* __restrict__ xml) {
  __shared__ unsigned long long masks[4];
  __shared__ int mbuf[256];
  const int blk = blockIdx.x;             // B_*ND_
  const int bz = blk >> 10, d = blk & 1023;
  const int tid = threadIdx.x;
  const int lane = tid & 63, wv = tid >> 6;
  const int c0 = tid * 4;
  const int nbase = bz * NA_;
  float4 acc = *(const float4*)(x + ((size_t)bz * N_ + b_idx[d]) * C_ + c0);
  int total_cnt = 0;
  for (int ch = 0; ch < NA_; ch += 256) {
    const int j = ch + tid;
    const bool m = (node_idx[nbase + j] == d);
    const unsigned long long wm = __ballot(m);
    if (lane == 0) masks[wv] = wm;
    __syncthreads();
    int before = 0, tot = 0;
#pragma unroll
    for (int w = 0; w < 4; w++) {
      const unsigned long long mk = masks[w];
      const int pc = __popcll(mk);
      tot += pc;
      if (w < wv) before += pc;
    }
    before += __popcll(wm & ((1ull << lane) - 1ull));
    if (m) mbuf[before] = j;
    __syncthreads();
    for (int k = 0; k < tot; k++) {
      const int i = mbuf[k];
      const float4 v = *(const float4*)(x + ((size_t)bz * N_ + a_idx[i]) * C_ + c0);
      acc.x += v.x; acc.y += v.y; acc.z += v.z; acc.w += v.w;
    }
    total_cnt += tot;
    __syncthreads();   // protect masks/mbuf before next chunk
  }
  const float s = 1.0f + (float)total_cnt;
  const float f[4] = {acc.x / s, acc.y / s, acc.z / s, acc.w / s};
  unsigned h4[4], l4[4];
#pragma unroll
  for (int j = 0; j < 4; j++) {
    h4[j] = f2bf_rtne(f[j]);
    const float fh = __uint_as_float(h4[j] << 16);
    l4[j] = f2bf_rtne(f[j] - fh);
  }
  uint2 ph, pl;
  ph.x = h4[0] | (h4[1] << 16); ph.y = h4[2] | (h4[3] << 16);
  pl.x = l4[0] | (l4[1] << 16); pl.y = l4[2] | (l4[3] << 16);
  const size_t o = (size_t)blk * C_ + c0;
  *(uint2*)&xmh[o] = ph;
  *(uint2*)&xml[o] = pl;
}

// ---------------------------------------------------------------------------
// K10: qkv GEMM via bf16x3 MFMA, software-pipelined.
// Epilogue writes Q(x0.125)/K [b,h,t,d] and V transposed [b,h,d,t], all hi/lo.
// ---------------------------------------------------------------------------
__global__ __launch_bounds__(256) void k_qkv_mfma(
    const unsigned short* __restrict__ xmh, const unsigned short* __restrict__ xml,
    const unsigned short* __restrict__ wqh, const unsigned short* __restrict__ wql,
    unsigned short* __restrict__ gqh, unsigned short* __restrict__ gql,
    unsigned short* __restrict__ gkh, unsigned short* __restrict__ gkl,
    unsigned short* __restrict__ gvh, unsigned short* __restrict__ gvl) {
  __shared__ __align__(16) unsigned short Ahs[128][40], Als[128][40];
  __shared__ __align__(16) unsigned short Bhs[128][40], Bls[128][40];
  const int nb = blockIdx.x;   // 24
  const int mb = blockIdx.y;   // 32
  const int tid = threadIdx.x;
  const int lane = tid & 63, wv = tid >> 6;
  const int wr = wv >> 1, wc = wv & 1;
  const int fr = lane & 15, fg = lane >> 4;
  const int srow = tid >> 1, scol = (tid & 1) * 16;
  const size_t abase = (size_t)(mb * 128 + srow) * C_ + scol;
  const size_t bbase = (size_t)(nb * 128 + srow) * C_ + scol;
  uint4 rah0 = *(const uint4*)(xmh + abase),    rah1 = *(const uint4*)(xmh + abase + 8);
  uint4 ral0 = *(const uint4*)(xml + abase),    ral1 = *(const uint4*)(xml + abase + 8);
  uint4 rbh0 = *(const uint4*)(wqh + bbase),    rbh1 = *(const uint4*)(wqh + bbase + 8);
  uint4 rbl0 = *(const uint4*)(wql + bbase),    rbl1 = *(const uint4*)(wql + bbase + 8);
  f32x4 acc[4][4] = {};
  for (int k0 = 0; k0 < C_; k0 += 32) {
    __syncthreads();
    *(uint4*)&Ahs[srow][scol]     = rah0;  *(uint4*)&Ahs[srow][scol + 8] = rah1;
    *(uint4*)&Als[srow][scol]     = ral0;  *(uint4*)&Als[srow][scol + 8] = ral1;
    *(uint4*)&Bhs[srow][scol]     = rbh0;  *(uint4*)&Bhs[srow][scol + 8] = rbh1;
    *(uint4*)&Bls[srow][scol]     = rbl0;  *(uint4*)&Bls[srow][scol + 8] = rbl1;
    if (k0 + 32 < C_) {
      const int kn = k0 + 32;
      rah0 = *(const uint4*)(xmh + abase + kn); rah1 = *(const uint4*)(xmh + abase + kn + 8);
      ral0 = *(const uint4*)(xml + abase + kn); ral1 = *(const uint4*)(xml + abase + kn + 8);
      rbh0 = *(const uint4*)(wqh + bbase + kn); rbh1 = *(const uint4*)(wqh + bbase + kn + 8);
      rbl0 = *(const uint4*)(wql + bbase + kn); rbl1 = *(const uint4*)(wql + bbase + kn + 8);
    }
    __syncthreads();
    short8v bh[4], bl[4];
#pragma unroll
    for (int j = 0; j < 4; j++) {
      bh[j] = *(const short8v*)&Bhs[wc * 64 + j * 16 + fr][fg * 8];
      bl[j] = *(const short8v*)&Bls[wc * 64 + j * 16 + fr][fg * 8];
    }
#pragma unroll
    for (int i = 0; i < 4; i++) {
      const short8v ah = *(const short8v*)&Ahs[wr * 64 + i * 16 + fr][fg * 8];
      const short8v al = *(const short8v*)&Als[wr * 64 + i * 16 + fr][fg * 8];
#pragma unroll
      for (int j = 0; j < 4; j++) {
        acc[i][j] = __builtin_amdgcn_mfma_f32_16x16x32_bf16(al, bh[j], acc[i][j], 0, 0, 0);
        acc[i][j] = __builtin_amdgcn_mfma_f32_16x16x32_bf16(ah, bl[j], acc[i][j], 0, 0, 0);
        acc[i][j] = __builtin_amdgcn_mfma_f32_16x16x32_bf16(ah, bh[j], acc[i][j], 0, 0, 0);
      }
    }
  }
  // D layout: col(n within 16) = fr, row(m within 16) = fg*4 + r.
  const int nq = nb * 2 + wc;          // n>>6: 0..47
  const int w = nq >> 4, h = nq & 15;  // tensor / head
  const int bb = mb >> 3;              // batch
  const int tb = (mb & 7) * 128 + wr * 64;
  const size_t base = (size_t)(bb * 16 + h) * 65536;
  if (w < 2) {
    unsigned short* __restrict__ dh = (w == 0) ? gqh : gkh;
    unsigned short* __restrict__ dl = (w == 0) ? gql : gkl;
    const float sc = (w == 0) ? 0.125f : 1.0f;
#pragma unroll
    for (int i = 0; i < 4; i++)
#pragma unroll
      for (int j = 0; j < 4; j++) {
        const int dc = j * 16 + fr;
#pragma unroll
        for (int r = 0; r < 4; r++) {
          const int t = tb + i * 16 + fg * 4 + r;
          const float f = acc[i][j][r] * sc;
          const unsigned short hv = f2bf_rtne(f);
          const float fh = __uint_as_float((unsigned)hv << 16);
          const unsigned short lv = f2bf_rtne(f - fh);
          dh[base + (size_t)t * 64 + dc] = hv;
          dl[base + (size_t)t * 64 + dc] = lv;
        }
      }
  } else {
#pragma unroll
    for (int i = 0; i < 4; i++)
#pragma unroll
      for (int j = 0; j < 4; j++) {
        const int dc = j * 16 + fr;
        const int t0 = tb + i * 16 + fg * 4;
        unsigned hv[4], lv[4];
#pragma unroll
        for (int r = 0; r < 4; r++) {
          const float f = acc[i][j][r];
          hv[r] = f2bf_rtne(f);
          const float fh = __uint_as_float(hv[r] << 16);
          lv[r] = f2bf_rtne(f - fh);
        }
        uint2 ph, pl;
        ph.x = hv[0] | (hv[1] << 16); ph.y = hv[2] | (hv[3] << 16);
        pl.x = lv[0] | (lv[1] << 16); pl.y = lv[2] | (lv[3] << 16);
        *(uint2*)&gvh[base + (size_t)dc * 1024 + t0] = ph;
        *(uint2*)&gvl[base + (size_t)dc * 1024 + t0] = pl;
      }
  }
}

// ---------------------------------------------------------------------------
// K11: flash attention via bf16x3 MFMA (verified R4/R5).
// ---------------------------------------------------------------------------
__global__ __launch_bounds__(256, 3) void k_attn(
    const unsigned short* __restrict__ gqh, const unsigned short* __restrict__ gql,
    const unsigned short* __restrict__ gkh, const unsigned short* __restrict__ gkl,
    const unsigned short* __restrict__ gvh, const unsigned short* __restrict__ gvl,
    unsigned short* __restrict__ omh, unsigned short* __restrict__ oml) {
  __shared__ __align__(16) unsigned short Qh[64][64], Ql[64][64];
  __shared__ __align__(16) unsigned short KP[2][64][72];   // K hi/lo, then P fp32
  __shared__ __align__(16) unsigned short VTh[64][72], VTl[64][72];
  float* const Pf = (float*)&KP[0][0][0];                  // [64][68] fp32 view
  const int qb = blockIdx.x, h = blockIdx.y, bz = blockIdx.z;
  const int tid = threadIdx.x;
  const int lane = tid & 63, wv = tid >> 6;
  const int fr = lane & 15, fg = lane >> 4;
  const int lr = tid >> 2, lc = (tid & 3) * 16;
  const size_t hb = (size_t)(bz * 16 + h) * 65536;
  { // stage Q (already scaled by 0.125 in k_qkv), XOR-swizzled
    const size_t o0 = hb + (size_t)(qb * 64 + lr) * 64 + lc;
    const int sw = lr & 7, kb0 = lc >> 3;
    *(uint4*)&Qh[lr][((kb0 + 0) ^ sw) * 8] = *(const uint4*)(gqh + o0);
    *(uint4*)&Qh[lr][((kb0 + 1) ^ sw) * 8] = *(const uint4*)(gqh + o0 + 8);
    *(uint4*)&Ql[lr][((kb0 + 0) ^ sw) * 8] = *(const uint4*)(gql + o0);
    *(uint4*)&Ql[lr][((kb0 + 1) ^ sw) * 8] = *(const uint4*)(gql + o0 + 8);
  }
  f32x4 o_[4] = {};
  float m_r[4] = {-INFINITY, -INFINITY, -INFINITY, -INFINITY};
  float l_r[4] = {0.0f, 0.0f, 0.0f, 0.0f};
  float alpha[4];
  for (int kt = 0; kt < 16; kt++) {
    __syncthreads();          // prev PV reads of KP(P)/VT done
    { // stage K rows + VT rows (pure coalesced copies, V pre-transposed)
      const size_t ko = hb + (size_t)(kt * 64 + lr) * 64 + lc;
      *(uint4*)&KP[0][lr][lc]     = *(const uint4*)(gkh + ko);
      *(uint4*)&KP[0][lr][lc + 8] = *(const uint4*)(gkh + ko + 8);
      *(uint4*)&KP[1][lr][lc]     = *(const uint4*)(gkl + ko);
      *(uint4*)&KP[1][lr][lc + 8] = *(const uint4*)(gkl + ko + 8);
      const size_t vo = hb + (size_t)lr * 1024 + kt * 64 + lc;
      *(uint4*)&VTh[lr][lc]     = *(const uint4*)(gvh + vo);
      *(uint4*)&VTh[lr][lc + 8] = *(const uint4*)(gvh + vo + 8);
      *(uint4*)&VTl[lr][lc]     = *(const uint4*)(gvl + vo);
      *(uint4*)&VTl[lr][lc + 8] = *(const uint4*)(gvl + vo + 8);
    }
    __syncthreads();          // staging visible
    // QK^T: S[q][k] = Q . K (both row-frags -> D = A*B^T), bf16x3
    f32x4 sacc[4] = {};
#pragma unroll
    for (int ks = 0; ks < 2; ks++) {
      const int kb = ks * 4 + fg;
      const short8v qh_ = *(const short8v*)&Qh[wv * 16 + fr][(kb ^ (fr & 7)) * 8];
      const short8v ql_ = *(const short8v*)&Ql[wv * 16 + fr][(kb ^ (fr & 7)) * 8];
#pragma unroll
      for (int nn = 0; nn < 4; nn++) {
        const short8v kh_ = *(const short8v*)&KP[0][nn * 16 + fr][ks * 32 + fg * 8];
        const short8v kl_ = *(const short8v*)&KP[1][nn * 16 + fr][ks * 32 + fg * 8];
        sacc[nn] = __builtin_amdgcn_mfma_f32_16x16x32_bf16(ql_, kh_, sacc[nn], 0, 0, 0);
        sacc[nn] = __builtin_amdgcn_mfma_f32_16x16x32_bf16(qh_, kl_, sacc[nn], 0, 0, 0);
        sacc[nn] = __builtin_amdgcn_mfma_f32_16x16x32_bf16(qh_, kh_, sacc[nn], 0, 0, 0);
      }
    }
    // online softmax (rows = fg*4 + r, cols spread over 16 lanes x 4 nn)
#pragma unroll
    for (int r = 0; r < 4; r++) {
      float tmax = fmaxf(fmaxf(sacc[0][r], sacc[1][r]), fmaxf(sacc[2][r], sacc[3][r]));
#pragma unroll
      for (int off = 8; off; off >>= 1) tmax = fmaxf(tmax, __shfl_xor(tmax, off, 16));
      const float mn = fmaxf(m_r[r], tmax);
      alpha[r] = expf(m_r[r] - mn);
      float s_ = 0.0f;
#pragma unroll
      for (int nn = 0; nn < 4; nn++) { sacc[nn][r] = expf(sacc[nn][r] - mn); s_ += sacc[nn][r]; }
#pragma unroll
      for (int off = 8; off; off >>= 1) s_ += __shfl_xor(s_, off, 16);
      m_r[r] = mn;
      l_r[r] = l_r[r] * alpha[r] + s_;
    }
    __syncthreads();          // all K-frag reads done -> overwrite region as P
#pragma unroll
    for (int nn = 0; nn < 4; nn++)
#pragma unroll
      for (int r = 0; r < 4; r++)
        Pf[(wv * 16 + fg * 4 + r) * 68 + nn * 16 + fr] = sacc[nn][r];
    __syncthreads();          // P visible (cross-lane)
#pragma unroll
    for (int nd = 0; nd < 4; nd++)
#pragma unroll
      for (int r = 0; r < 4; r++) o_[nd][r] *= alpha[r];
    // PV: O[q][d] = P . V = A(P rows) * B(VT rows)^T, bf16x3
#pragma unroll
    for (int ks = 0; ks < 2; ks++) {
      float pf[8];
      *(float4*)&pf[0] = *(const float4*)&Pf[(wv * 16 + fr) * 68 + ks * 32 + fg * 8];
      *(float4*)&pf[4] = *(const float4*)&Pf[(wv * 16 + fr) * 68 + ks * 32 + fg * 8 + 4];
      short8v ph_, pl_;
      split8(pf, ph_, pl_);
#pragma unroll
      for (int nd = 0; nd < 4; nd++) {
        const short8v vh_ = *(const short8v*)&VTh[nd * 16 + fr][ks * 32 + fg * 8];
        const short8v vl_ = *(const short8v*)&VTl[nd * 16 + fr][ks * 32 + fg * 8];
        o_[nd] = __builtin_amdgcn_mfma_f32_16x16x32_bf16(pl_, vh_, o_[nd], 0, 0, 0);
        o_[nd] = __builtin_amdgcn_mfma_f32_16x16x32_bf16(ph_, vl_, o_[nd], 0, 0, 0);
        o_[nd] = __builtin_amdgcn_mfma_f32_16x16x32_bf16(ph_, vh_, o_[nd], 0, 0, 0);
      }
    }
  }
  // epilogue: bf16 hi/lo om for MFMA proj. col = fr (d in 16-block), row = fg*4+r.
#pragma unroll
  for (int r = 0; r < 4; r++) {
    const float inv = 1.0f / l_r[r];
    const int t = qb * 64 + wv * 16 + fg * 4 + r;
    const size_t ob = (size_t)(bz * ND_ + t) * C_ + h * 64;
#pragma unroll
    for (int nd = 0; nd < 4; nd++) {
      const float f = o_[nd][r] * inv;
      const unsigned short hv = f2bf_rtne(f);
      const float fh = __uint_as_float((unsigned)hv << 16);
      const unsigned short lv = f2bf_rtne(f - fh);
      omh[ob + nd * 16 + fr] = hv;
      oml[ob + nd * 16 + fr] = lv;
    }
  }
}

// ---------------------------------------------------------------------------
// K12: proj GEMM via bf16x3 MFMA, software-pipelined. ym = om@Wp^T + bp
// ---------------------------------------------------------------------------
__global__ __launch_bounds__(256) void k_proj_mfma(
    const unsigned short* __restrict__ omh, const unsigned short* __restrict__ oml,
    const unsigned short* __restrict__ wph, const unsigned short* __restrict__ wpl,
    const float* __restrict__ bp, float* __restrict__ ym) {
  __shared__ __align__(16) unsigned short Ahs[128][40], Als[128][40];
  __shared__ __align__(16) unsigned short Bhs[128][40], Bls[128][40];
  const int nb = blockIdx.x;   // 8
  const int mb = blockIdx.y;   // 32
  const int tid = threadIdx.x;
  const int lane = tid & 63, wv = tid >> 6;
  const int wr = wv >> 1, wc = wv & 1;
  const int fr = lane & 15, fg = lane >> 4;
  const int srow = tid >> 1, scol = (tid & 1) * 16;
  const size_t abase = (size_t)(mb * 128 + srow) * C_ + scol;
  const size_t bbase = (size_t)(nb * 128 + srow) * C_ + scol;
  uint4 rah0 = *(const uint4*)(omh + abase),    rah1 = *(const uint4*)(omh + abase + 8);
  uint4 ral0 = *(const uint4*)(oml + abase),    ral1 = *(const uint4*)(oml + abase + 8);
  uint4 rbh0 = *(const uint4*)(wph + bbase),    rbh1 = *(const uint4*)(wph + bbase + 8);
  uint4 rbl0 = *(const uint4*)(wpl + bbase),    rbl1 = *(const uint4*)(wpl + bbase + 8);
  f32x4 acc[4][4] = {};
  for (int k0 = 0; k0 < C_; k0 += 32) {
    __syncthreads();
    *(uint4*)&Ahs[srow][scol]     = rah0;  *(uint4*)&Ahs[srow][scol + 8] = rah1;
    *(uint4*)&Als[srow][scol]     = ral0;  *(uint4*)&Als[srow][scol + 8] = ral1;
    *(uint4*)&Bhs[srow][scol]     = rbh0;  *(uint4*)&Bhs[srow][scol + 8] = rbh1;
    *(uint4*)&Bls[srow][scol]     = rbl0;  *(uint4*)&Bls[srow][scol + 8] = rbl1;
    if (k0 + 32 < C_) {
      const int kn = k0 + 32;
      rah0 = *(const uint4*)(omh + abase + kn); rah1 = *(const uint4*)(omh + abase + kn + 8);
      ral0 = *(const uint4*)(oml + abase + kn); ral1 = *(const uint4*)(oml + abase + kn + 8);
      rbh0 = *(const uint4*)(wph + bbase + kn); rbh1 = *(const uint4*)(wph + bbase + kn + 8);
      rbl0 = *(const uint4*)(wpl + bbase + kn); rbl1 = *(const uint4*)(wpl + bbase + kn + 8);
    }
    __syncthreads();
    short8v bh[4], bl[4];
#pragma unroll
    for (int j = 0; j < 4; j++) {
      bh[j] = *(const short8v*)&Bhs[wc * 64 + j * 16 + fr][fg * 8];
      bl[j] = *(const short8v*)&Bls[wc * 64 + j * 16 + fr][fg * 8];
    }
#pragma unroll
    for (int i = 0; i < 4; i++) {
      const short8v ah = *(const short8v*)&Ahs[wr * 64 + i * 16 + fr][fg * 8];
      const short8v al = *(const short8v*)&Als[wr * 64 + i * 16 + fr][fg * 8];
#pragma unroll
      for (int j = 0; j < 4; j++) {
        acc[i][j] = __builtin_amdgcn_mfma_f32_16x16x32_bf16(al, bh[j], acc[i][j], 0, 0, 0);
        acc[i][j] = __builtin_amdgcn_mfma_f32_16x16x32_bf16(ah, bl[j], acc[i][j], 0, 0, 0);
        acc[i][j] = __builtin_amdgcn_mfma_f32_16x16x32_bf16(ah, bh[j], acc[i][j], 0, 0, 0);
      }
    }
  }
#pragma unroll
  for (int j = 0; j < 4; j++) {
    const int n = nb * 128 + wc * 64 + j * 16 + fr;
    const float bias = bp[n];
#pragma unroll
    for (int i = 0; i < 4; i++)
#pragma unroll
      for (int r = 0; r < 4; r++) {
        const int m = mb * 128 + wr * 64 + i * 16 + fg * 4 + r;
        ym[(size_t)m * C_ + n] = acc[i][j][r] + bias;
      }
  }
}

// K13: scatter merged rows back to all 4096 tokens
__global__ __launch_bounds__(256) void k_unmerge(const float* __restrict__ ym,
                                                 const int* __restrict__ rowmap,
                                                 float* __restrict__ out) {
  const int blk = blockIdx.x;                 // B_*N_
  const int bz = blk >> 12;
  const int r = rowmap[blk];
  const float4* src = (const float4*)(ym + ((size_t)bz * ND_ + r) * C_);
  float4* dst = (float4*)(out + (size_t)blk * C_);
  dst[threadIdx.x] = src[threadIdx.x];
}

// ---------------------------------------------------------------------------
extern "C" void kernel_launch(void* const* d_in, const int* in_sizes, int n_in,
                              void* d_out, int out_size, void* d_ws, size_t ws_size,
                              hipStream_t stream) {
  const float* x    = (const float*)d_in[0];
  const float* Wqkv = (const float*)d_in[1];
  const float* Wp   = (const float*)d_in[2];
  const float* bp   = (const float*)d_in[3];
  char* ws = (char*)d_ws;
  double* dinv    = (double*)(ws + 0);          //  131072 B
  int*   b_idx    = (int*)(ws + 131072);
  int*   a_idx    = (int*)(ws + 135168);
  int*   node_idx = (int*)(ws + 147456);
  int*   rowmap   = (int*)(ws + 212992);
  int*   flaglist = (int*)(ws + 278528);        // 49152 B (<= B_*NA_ ids)
  float* pv1      = (float*)(ws + 327680);      // 393216 B used (8 tiles)
  int*   nflag    = (int*)(ws + 720896);        // 4 B, in pv1's unused tail
  int*   pi1      = (int*)(ws + 1114112);
  float* pv2      = (float*)(ws + 1900544);
  int*   pi2      = (int*)(ws + 2686976);
  // Lifetime-disjoint aliased regions (all hand-checked, stream-ordered):
  // [3,473,408 .. 70,582,272): xh/xl (prep->scores)
  unsigned short* xh = (unsigned short*)(ws + 3473408);    // 33,554,432 B
  unsigned short* xl = (unsigned short*)(ws + 37027840);   // 33,554,432 B
  // xmh/xml (merge_fused->qkv) alias xh tail
  unsigned short* xmh = (unsigned short*)(ws + 20250624);  // 8,388,608 B
  unsigned short* xml = (unsigned short*)(ws + 28639232);  // 8,388,608 B
  // Wq hi/lo (prep_w->qkv) alias xl head
  unsigned short* wqh = (unsigned short*)(ws + 37027840);  // 6,291,456 B
  unsigned short* wql = (unsigned short*)(ws + 43319296);  // 6,291,456 B
  // Q/K/V hi-lo (qkv->attn): Q aliases dead xh head; K/V in fresh region
  unsigned short* gqh = (unsigned short*)(ws + 3473408);   // 8,388,608 B
  unsigned short* gql = (unsigned short*)(ws + 11862016);  // 8,388,608 B
  unsigned short* gkh = (unsigned short*)(ws + 49610752);  // 8,388,608 B
  unsigned short* gkl = (unsigned short*)(ws + 57999360);  // 8,388,608 B
  unsigned short* gvh = (unsigned short*)(ws + 66387968);  // 8,388,608 B
  unsigned short* gvl = (unsigned short*)(ws + 74776576);  // 8,388,608 B  (ends 83,165,184)
  // Wp hi/lo (prep_w->proj), tail region
  unsigned short* wph = (unsigned short*)(ws + 83165184);  // 2,097,152 B
  unsigned short* wpl = (unsigned short*)(ws + 85262336);  // 2,097,152 B  (ends 87,359,488)
  // om hi/lo (attn->proj) alias dead xmh/xml
  unsigned short* omh = (unsigned short*)(ws + 20250624);  // 8,388,608 B
  unsigned short* oml = (unsigned short*)(ws + 28639232);  // 8,388,608 B
  // ym fp32 (proj->unmerge) aliases dead gqh/gql
  float* ym = (float*)(ws + 3473408);                      // 16,777,216 B
  float* out = (float*)d_out;

  hipMemsetAsync(nflag, 0, sizeof(int), stream);
  k_init_indices<<<1, 1024, 0, stream>>>(b_idx, a_idx);
  k_row_norms<<<B_ * N_, 256, 0, stream>>>(x, dinv);
  k_prep<<<B_ * N_, 256, 0, stream>>>(x, dinv, xh, xl);
  k_scores_mfma<<<dim3(8, 24, B_), 256, 0, stream>>>(xh, xl, a_idx, b_idx, pv1, pi1, pv2, pi2);
  k_prep_w<<<4096, 256, 0, stream>>>(Wqkv, Wp, wqh, wql, wph, wpl);  // after scores (xl dead)
  k_finalize<<<(B_ * NA_) / 256, 256, 0, stream>>>(pv1, pi1, pv2, pi2, node_idx, flaglist, nflag);
  k_recheck<<<1536, 256, 0, stream>>>(x, dinv, a_idx, b_idx, pv1, pi1, pv2, pi2,
                                      flaglist, nflag, node_idx);
  k_rowmap<<<(B_ * N_) / 256, 256, 0, stream>>>(a_idx, b_idx, node_idx, rowmap);
  k_merge_fused<<<B_ * ND_, 256, 0, stream>>>(x, a_idx, b_idx, node_idx, xmh, xml);
  k_qkv_mfma<<<dim3(24, 32), 256, 0, stream>>>(xmh, xml, wqh, wql,
                                               gqh, gql, gkh, gkl, gvh, gvl);
  k_attn<<<dim3(16, 16, B_), 256, 0, stream>>>(gqh, gql, gkh, gkl, gvh, gvl, omh, oml);
  k_proj_mfma<<<dim3(8, 32), 256, 0, stream>>>(omh, oml, wph, wpl, bp, ym);
  k_unmerge<<<B_ * N_, 256, 0, stream>>>(ym, rowmap, out);
}

// Round 12
// 727.034 us; speedup vs baseline: 1.1391x; 1.1391x over previous
//
#include <hip/hip_runtime.h>
#include <cmath>

// Problem constants (B,N,DIM,HEADS)=(4,4096,1024,16), SX=SY=2, ratio .9
#define B_  4
#define N_  4096
#define C_  1024
#define H_  16
#define D_  64
#define ND_ 1024   // num dst tokens (one per 2x2 block)
#define NA_ 3072   // num src (a) tokens
// r = min(3072, int(4096*0.9)) = 3072  => unm empty, sort permutation cancels.

typedef __attribute__((ext_vector_type(8))) short short8v;
typedef __attribute__((ext_vector_type(4))) float f32x4;

// ---------------------------------------------------------------------------
// threefry2x32 (20 rounds), returns BOTH output words.
// ---------------------------------------------------------------------------
__device__ inline void tf2x32(unsigned k0, unsigned k1, unsigned x0, unsigned x1,
                              unsigned& o0, unsigned& o1) {
  const unsigned ks2 = 0x1BD11BDAu ^ k0 ^ k1;
  x0 += k0; x1 += k1;
#define RND_(r) { x0 += x1; x1 = (x1 << (r)) | (x1 >> (32 - (r))); x1 ^= x0; }
  RND_(13) RND_(15) RND_(26) RND_(6)
  x0 += k1;  x1 += ks2 + 1u;
  RND_(17) RND_(29) RND_(16) RND_(24)
  x0 += ks2; x1 += k0 + 2u;
  RND_(13) RND_(15) RND_(26) RND_(6)
  x0 += k0;  x1 += k1 + 3u;
  RND_(17) RND_(29) RND_(16) RND_(24)
  x0 += k1;  x1 += ks2 + 4u;
  RND_(13) RND_(15) RND_(26) RND_(6)
  x0 += ks2; x1 += k0 + 5u;
#undef RND_
  o0 = x0; o1 = x1;
}

// ---------------------------------------------------------------------------
// K1 (VERIFIED r7): jax.random.randint(key(33),(32,32),0,4)
// ---------------------------------------------------------------------------
__global__ __launch_bounds__(1024) void k_init_indices(int* __restrict__ b_idx,
                                                       int* __restrict__ a_idx) {
  __shared__ unsigned char randk[1024];
  __shared__ int wtot[16], wpre[16];
  const int tid = threadIdx.x;
  {
    unsigned c0, c1;
    tf2x32(0u, 33u, 0u, 1u, c0, c1);                 // k2 = split(key)[1]
    unsigned d0, d1;
    tf2x32(c0, c1, 0u, (unsigned)tid, d0, d1);       // random_bits element p
    randk[tid] = (unsigned char)((d0 ^ d1) & 3u);    // xor-fold, % span
  }
  __syncthreads();
  const int base_t = tid * 4;
  int f[4]; int cnt = 0;
#pragma unroll
  for (int j = 0; j < 4; j++) {
    const int t = base_t + j;
    const int y = t >> 6, xc = t & 63;
    const int bi = (y >> 1) * 32 + (xc >> 1);
    const int k  = (y & 1) * 2 + (xc & 1);
    f[j] = (randk[bi] == (unsigned char)k) ? 1 : 0;
    cnt += f[j];
  }
  const int lane = tid & 63, wave = tid >> 6;
  int incl = cnt;
#pragma unroll
  for (int off = 1; off < 64; off <<= 1) {
    int nb = __shfl_up(incl, off, 64);
    if (lane >= off) incl += nb;
  }
  if (lane == 63) wtot[wave] = incl;
  __syncthreads();
  if (tid == 0) { int s = 0; for (int w = 0; w < 16; w++) { wpre[w] = s; s += wtot[w]; } }
  __syncthreads();
  int P = wpre[wave] + (incl - cnt);   // #dst strictly before base_t
#pragma unroll
  for (int j = 0; j < 4; j++) {
    const int t = base_t + j;
    if (f[j]) { b_idx[P] = t; P++; }
    else      { a_idx[t - P] = t; }
  }
}

// ---------------------------------------------------------------------------
// K2: per-token inverse L2 norm of x, fp64
// ---------------------------------------------------------------------------
__global__ __launch_bounds__(256) void k_row_norms(const float* __restrict__ x,
                                                   double* __restrict__ dinv) {
  const int row = blockIdx.x;                 // B_*N_
  const float* xr = x + (size_t)row * C_;
  const int tid = threadIdx.x;
  float4 v = ((const float4*)xr)[tid];
  double s = (double)v.x * (double)v.x + (double)v.y * (double)v.y +
             (double)v.z * (double)v.z + (double)v.w * (double)v.w;
#pragma unroll
  for (int off = 32; off; off >>= 1) s += __shfl_down(s, off, 64);
  __shared__ double wsum[4];
  if ((tid & 63) == 0) wsum[tid >> 6] = s;
  __syncthreads();
  if (tid == 0) {
    double t = wsum[0] + wsum[1] + wsum[2] + wsum[3];
    dinv[row] = 1.0 / sqrt(t);
  }
}

// ---------------------------------------------------------------------------
// bf16 split helpers (RTNE)
// ---------------------------------------------------------------------------
__device__ inline unsigned short f2bf_rtne(float f) {
  const unsigned u = __float_as_uint(f);
  return (unsigned short)((u + 0x7FFFu + ((u >> 16) & 1u)) >> 16);
}

__device__ inline void split8(const float* f, short8v& h8, short8v& l8) {
#pragma unroll
  for (int j = 0; j < 8; j++) {
    const unsigned short hv = f2bf_rtne(f[j]);
    const float fh = __uint_as_float((unsigned)hv << 16);
    const unsigned short lv = f2bf_rtne(f[j] - fh);
    h8[j] = (short)hv; l8[j] = (short)lv;
  }
}

// ---------------------------------------------------------------------------
// K2b: normalized rows split into bf16 hi + bf16 lo (RTNE), for MFMA scores.
// ---------------------------------------------------------------------------
__global__ __launch_bounds__(256) void k_prep(const float* __restrict__ x,
                                              const double* __restrict__ dinv,
                                              unsigned short* __restrict__ xh,
                                              unsigned short* __restrict__ xl) {
  const int row = blockIdx.x;                 // B_*N_
  const float ia = (float)dinv[row];
  const float4 v = ((const float4*)(x + (size_t)row * C_))[threadIdx.x];
  float f[4] = {v.x * ia, v.y * ia, v.z * ia, v.w * ia};
  unsigned h[4], l[4];
#pragma unroll
  for (int j = 0; j < 4; j++) {
    h[j] = f2bf_rtne(f[j]);
    const float fh = __uint_as_float(h[j] << 16);
    l[j] = f2bf_rtne(f[j] - fh);
  }
  const size_t o = (size_t)row * C_ + threadIdx.x * 4;
  uint2 ph, pl;
  ph.x = h[0] | (h[1] << 16); ph.y = h[2] | (h[3] << 16);
  pl.x = l[0] | (l[1] << 16); pl.y = l[2] | (l[3] << 16);
  *(uint2*)&xh[o] = ph;
  *(uint2*)&xl[o] = pl;
}

// ---------------------------------------------------------------------------
// K2c: split Wqkv (3072x1024) and Wp (1024x1024) into bf16 hi/lo.
// ---------------------------------------------------------------------------
__global__ __launch_bounds__(256) void k_prep_w(const float* __restrict__ Wqkv,
                                                const float* __restrict__ Wp,
                                                unsigned short* __restrict__ wqh,
                                                unsigned short* __restrict__ wql,
                                                unsigned short* __restrict__ wph,
                                                unsigned short* __restrict__ wpl) {
  const int row = blockIdx.x;            // 0..4095
  const float* src;
  unsigned short *dh, *dl;
  size_t o;
  if (row < 3072) { src = Wqkv + (size_t)row * C_; dh = wqh; dl = wql; o = (size_t)row * C_; }
  else { src = Wp + (size_t)(row - 3072) * C_; dh = wph; dl = wpl; o = (size_t)(row - 3072) * C_; }
  const float4 v = ((const float4*)src)[threadIdx.x];
  const float f[4] = {v.x, v.y, v.z, v.w};
  unsigned h4[4], l4[4];
#pragma unroll
  for (int j = 0; j < 4; j++) {
    h4[j] = f2bf_rtne(f[j]);
    const float fh = __uint_as_float(h4[j] << 16);
    l4[j] = f2bf_rtne(f[j] - fh);
  }
  uint2 ph, pl;
  ph.x = h4[0] | (h4[1] << 16); ph.y = h4[2] | (h4[3] << 16);
  pl.x = l4[0] | (l4[1] << 16); pl.y = l4[2] | (l4[3] << 16);
  *(uint2*)&dh[o + threadIdx.x * 4] = ph;
  *(uint2*)&dl[o + threadIdx.x * 4] = pl;
}

// top-2 merge tracking both indices
__device__ inline void top2m(float& v1, int& i1, float& v2, int& i2,
                             float ov1, int oi1, float ov2, int oi2) {
  if (ov1 > v1 || (ov1 == v1 && oi1 < i1)) {
    if (v1 > ov2 || (v1 == ov2 && i1 < oi2)) { v2 = v1; i2 = i1; }
    else { v2 = ov2; i2 = oi2; }
    v1 = ov1; i1 = oi1;
  } else if (ov1 > v2 || (ov1 == v2 && oi1 < i2)) {
    v2 = ov1; i2 = oi1;
  }
}

// ---------------------------------------------------------------------------
// K3: scores via bf16x3 MFMA, 128x128 tile, BK=32, software-pipelined
// (REVERTED from R11's direct-L2: staged LDS + register prefetch is the
// latency-hiding structure; barriers were not the cost).
// Epilogue mv/mi arrays alias the tile LDS (dead after K-loop + barrier):
// LDS = 40,960 B exactly -> 4 blocks/CU (was 45,056 -> 3).
// ---------------------------------------------------------------------------
__global__ __launch_bounds__(256) void k_scores_mfma(
    const unsigned short* __restrict__ xh, const unsigned short* __restrict__ xl,
    const int* __restrict__ a_idx, const int* __restrict__ b_idx,
    float* __restrict__ pv1, int* __restrict__ pi1,
    float* __restrict__ pv2, int* __restrict__ pi2) {
  __shared__ __align__(16) unsigned short Ahs[128][40], Als[128][40];
  __shared__ __align__(16) unsigned short Bhs[128][40], Bls[128][40];
  // epilogue unions (each [128][2]; tiles dead after the post-loop barrier)
  float* const mv1 = (float*)&Ahs[0][0];
  float* const mv2 = (float*)&Als[0][0];
  int*   const mi1 = (int*)&Bhs[0][0];
  int*   const mi2 = (int*)&Bls[0][0];
  const int bz = blockIdx.z, cb = blockIdx.x, sb = blockIdx.y;  // cb: 8, sb: 24
  const int tid = threadIdx.x;
  const int lane = tid & 63, wv = tid >> 6;
  const int wr = wv >> 1, wc = wv & 1;
  const int fr = lane & 15, fg = lane >> 4;
  const int srow = tid >> 1, scol = (tid & 1) * 16;
  const int ga = a_idx[sb * 128 + srow];
  const int gb = b_idx[cb * 128 + srow];
  const size_t abase = ((size_t)bz * N_ + ga) * C_ + scol;
  const size_t bbase = ((size_t)bz * N_ + gb) * C_ + scol;
  // prefetch K-tile 0
  uint4 rah0 = *(const uint4*)(xh + abase),     rah1 = *(const uint4*)(xh + abase + 8);
  uint4 ral0 = *(const uint4*)(xl + abase),     ral1 = *(const uint4*)(xl + abase + 8);
  uint4 rbh0 = *(const uint4*)(xh + bbase),     rbh1 = *(const uint4*)(xh + bbase + 8);
  uint4 rbl0 = *(const uint4*)(xl + bbase),     rbl1 = *(const uint4*)(xl + bbase + 8);
  f32x4 acc[4][4] = {};
  for (int k0 = 0; k0 < C_; k0 += 32) {
    __syncthreads();
    *(uint4*)&Ahs[srow][scol]     = rah0;  *(uint4*)&Ahs[srow][scol + 8] = rah1;
    *(uint4*)&Als[srow][scol]     = ral0;  *(uint4*)&Als[srow][scol + 8] = ral1;
    *(uint4*)&Bhs[srow][scol]     = rbh0;  *(uint4*)&Bhs[srow][scol + 8] = rbh1;
    *(uint4*)&Bls[srow][scol]     = rbl0;  *(uint4*)&Bls[srow][scol + 8] = rbl1;
    if (k0 + 32 < C_) {   // issue next-tile loads; latency hides under MFMA below
      const int kn = k0 + 32;
      rah0 = *(const uint4*)(xh + abase + kn); rah1 = *(const uint4*)(xh + abase + kn + 8);
      ral0 = *(const uint4*)(xl + abase + kn); ral1 = *(const uint4*)(xl + abase + kn + 8);
      rbh0 = *(const uint4*)(xh + bbase + kn); rbh1 = *(const uint4*)(xh + bbase + kn + 8);
      rbl0 = *(const uint4*)(xl + bbase + kn); rbl1 = *(const uint4*)(xl + bbase + kn + 8);
    }
    __syncthreads();
    short8v bh[4], bl[4];
#pragma unroll
    for (int j = 0; j < 4; j++) {
      bh[j] = *(const short8v*)&Bhs[wc * 64 + j * 16 + fr][fg * 8];
      bl[j] = *(const short8v*)&Bls[wc * 64 + j * 16 + fr][fg * 8];
    }
#pragma unroll
    for (int i = 0; i < 4; i++) {
      const short8v ah = *(const short8v*)&Ahs[wr * 64 + i * 16 + fr][fg * 8];
      const short8v al = *(const short8v*)&Als[wr * 64 + i * 16 + fr][fg * 8];
#pragma unroll
      for (int j = 0; j < 4; j++) {
        acc[i][j] = __builtin_amdgcn_mfma_f32_16x16x32_bf16(al, bh[j], acc[i][j], 0, 0, 0);
        acc[i][j] = __builtin_amdgcn_mfma_f32_16x16x32_bf16(ah, bl[j], acc[i][j], 0, 0, 0);
        acc[i][j] = __builtin_amdgcn_mfma_f32_16x16x32_bf16(ah, bh[j], acc[i][j], 0, 0, 0);
      }
    }
  }
  __syncthreads();   // all tile reads complete -> safe to alias LDS as mv/mi
  // top-2 epilogue. D layout: col = fr (within 16), row = fg*4 + r (m89).
#pragma unroll
  for (int i = 0; i < 4; i++) {
#pragma unroll
    for (int r = 0; r < 4; r++) {
      float v1 = acc[i][0][r]; int i1 = cb * 128 + wc * 64 + fr;
      float v2 = -INFINITY;    int i2 = i1;
#pragma unroll
      for (int j = 1; j < 4; j++) {
        const float v = acc[i][j][r];
        const int d = cb * 128 + wc * 64 + j * 16 + fr;
        if (v > v1) { v2 = v1; i2 = i1; v1 = v; i1 = d; }
        else if (v > v2) { v2 = v; i2 = d; }
      }
#pragma unroll
      for (int off = 8; off; off >>= 1) {
        const float ov1 = __shfl_xor(v1, off, 16);
        const int   oi1 = __shfl_xor(i1, off, 16);
        const float ov2 = __shfl_xor(v2, off, 16);
        const int   oi2 = __shfl_xor(i2, off, 16);
        top2m(v1, i1, v2, i2, ov1, oi1, ov2, oi2);
      }
      if (fr == 0) {
        const int rl = wr * 64 + i * 16 + fg * 4 + r;
        mv1[rl * 2 + wc] = v1; mi1[rl * 2 + wc] = i1;
        mv2[rl * 2 + wc] = v2; mi2[rl * 2 + wc] = i2;
      }
    }
  }
  __syncthreads();
  if (tid < 128) {
    float v1 = mv1[tid * 2 + 0], v2 = mv2[tid * 2 + 0];
    int   i1 = mi1[tid * 2 + 0], i2 = mi2[tid * 2 + 0];
    top2m(v1, i1, v2, i2, mv1[tid * 2 + 1], mi1[tid * 2 + 1],
          mv2[tid * 2 + 1], mi2[tid * 2 + 1]);
    const int s = sb * 128 + tid;
    const size_t o = ((size_t)bz * NA_ + s) * 8 + cb;
    pv1[o] = v1; pi1[o] = i1; pv2[o] = v2; pi2[o] = i2;
  }
}

// K4: merge 8 per-tile partials -> node_idx; append near-ties to flaglist.
// eps(bf16x3) <= ~1e-5; 2*eps ~= 2e-5. Flag at 1e-4 (5x margin): unflagged =>
// gap > 1e-4 > 2*eps => argmax exact.
__global__ __launch_bounds__(256) void k_finalize(
    const float* __restrict__ pv1, const int* __restrict__ pi1,
    const float* __restrict__ pv2, const int* __restrict__ pi2,
    int* __restrict__ node_idx, int* __restrict__ flaglist,
    int* __restrict__ nflag) {
  const int r = blockIdx.x * 256 + threadIdx.x;   // [0, B_*NA_)
  if (r >= B_ * NA_) return;
  size_t o = (size_t)r * 8;
  float v1 = pv1[o]; int i1 = pi1[o]; float v2 = pv2[o]; int i2 = pi2[o];
  for (int cb = 1; cb < 8; cb++)
    top2m(v1, i1, v2, i2, pv1[o + cb], pi1[o + cb], pv2[o + cb], pi2[o + cb]);
  node_idx[r] = i1;
  if (v1 - v2 < 1e-4f) flaglist[atomicAdd(nflag, 1)] = r;
}

// ---------------------------------------------------------------------------
// K5: fp64 recheck over COMPACTED flag list, persistent blocks.
// Candidate/scan threshold 5e-5; nc==1 early-out; 4-way ILP batches.
// ---------------------------------------------------------------------------
__global__ __launch_bounds__(256) void k_recheck(
    const float* __restrict__ x, const double* __restrict__ dinv,
    const int* __restrict__ a_idx, const int* __restrict__ b_idx,
    const float* __restrict__ pv1, const int* __restrict__ pi1,
    const float* __restrict__ pv2, const int* __restrict__ pi2,
    const int* __restrict__ flaglist, const int* __restrict__ nflag,
    int* __restrict__ node_idx) {
  __shared__ double arow[C_];
  __shared__ int cand[1088];
  __shared__ int ncand;
  __shared__ float v1s[8];
  __shared__ double bvs[4]; __shared__ int bis[4];
  const int tid = threadIdx.x;
  const int lane = tid & 63, wave = tid >> 6;
  const int nf = *nflag;
  for (int it = blockIdx.x; it < nf; it += gridDim.x) {
    const int r = flaglist[it];                 // bz*NA_ + s
    const int bz = r / NA_, s = r % NA_;
    const size_t o = (size_t)r * 8;
    if (tid < 8) v1s[tid] = pv1[o + tid];
    if (tid == 0) ncand = 0;
    __syncthreads();
    float v1g = v1s[0];
#pragma unroll
    for (int cb = 1; cb < 8; cb++) v1g = fmaxf(v1g, v1s[cb]);
    if (tid < 8) {
      const float tv1 = pv1[o + tid], tv2 = pv2[o + tid];
      if (tv2 >= v1g - 5e-5f) {
        // tile may hide more near-max entries -> scan whole 128-dst tile
        const int base = atomicAdd(&ncand, 128);
        for (int j = 0; j < 128; j++) cand[base + j] = tid * 128 + j;
      } else if (tv1 >= v1g - 5e-5f) {
        cand[atomicAdd(&ncand, 1)] = pi1[o + tid];
      }
    }
    __syncthreads();
    const int nc = ncand;
    if (nc == 1) { __syncthreads(); continue; }   // unique candidate = node_idx
    // stage a-row in fp64 (only when actually needed)
    const int ga = a_idx[s];
    const double ia = dinv[bz * N_ + ga];
    const float* xa = x + ((size_t)bz * N_ + ga) * C_;
    for (int c = tid; c < C_; c += 256) arow[c] = (double)xa[c] * ia;
    __syncthreads();
    double bv = -1e300; int bi = 1 << 30;
    for (int cb0 = wave * 4; cb0 < nc; cb0 += 16) {   // 4 candidates per wave batch
      double sum[4] = {0.0, 0.0, 0.0, 0.0};
      int dd[4]; const float* xb[4]; double ibv[4]; bool val[4];
#pragma unroll
      for (int u = 0; u < 4; u++) {
        const int ci = cb0 + u;
        val[u] = (ci < nc);
        const int dv = cand[val[u] ? ci : 0];
        dd[u] = dv;
        const int gb = b_idx[dv];
        ibv[u] = dinv[bz * N_ + gb];
        xb[u] = x + ((size_t)bz * N_ + gb) * C_;
      }
      for (int c = lane; c < C_; c += 64) {
        const double a = arow[c];
#pragma unroll
        for (int u = 0; u < 4; u++) sum[u] += a * ((double)xb[u][c] * ibv[u]);
      }
#pragma unroll
      for (int u = 0; u < 4; u++) {
#pragma unroll
        for (int off = 32; off; off >>= 1) sum[u] += __shfl_xor(sum[u], off, 64);
        if (val[u] && (sum[u] > bv || (sum[u] == bv && dd[u] < bi))) { bv = sum[u]; bi = dd[u]; }
      }
    }
    if (lane == 0) { bvs[wave] = bv; bis[wave] = bi; }
    __syncthreads();
    if (tid == 0) {
      for (int w = 1; w < 4; w++)
        if (bvs[w] > bv || (bvs[w] == bv && bis[w] < bi)) { bv = bvs[w]; bi = bis[w]; }
      node_idx[r] = bi;
    }
    __syncthreads();
  }
}

// K6: token->merged-row map
__global__ __launch_bounds__(256) void k_rowmap(
    const int* __restrict__ a_idx, const int* __restrict__ b_idx,
    const int* __restrict__ node_idx, int* __restrict__ rowmap) {
  const int i = blockIdx.x * 256 + threadIdx.x;   // [0, B_*N_)
  if (i >= B_ * N_) return;
  const int bz = i >> 12, j = i & 4095;
  if (j < NA_) {
    rowmap[bz * N_ + a_idx[j]] = node_idx[bz * NA_ + j];
  } else {
    const int d = j - NA_;
    rowmap[bz * N_ + b_idx[d]] = d;
  }
}

// ---------------------------------------------------------------------------
// K7 (fused merge): one block per (bz,dst). Scan node_idx for sources via
// ballot-compaction (deterministic ascending order), sum rows, scale, emit
// bf16 hi/lo directly.
// ---------------------------------------------------------------------------
__global__ __launch_bounds__(256) void k_merge_fused(
    const float* __restrict__ x, const int* __restrict__ a_idx,
    const int* __restrict__ b_idx, const int* __restrict__ node_idx,
    unsigned short* __restrict__ xmh, unsigned short* __restrict__ xml) {
  __shared__ unsigned long long masks[4];
  __shared__ int mbuf[256];
  const int blk = blockIdx.x;             // B_*ND_
  const int bz = blk >> 10, d = blk & 1023;
  const int tid = threadIdx.x;
  const int lane = tid & 63, wv = tid >> 6;
  const int c0 = tid * 4;
  const int nbase = bz * NA_;
  float4 acc = *(const float4*)(x + ((size_t)bz * N_ + b_idx[d]) * C_ + c0);
  int total_cnt = 0;
  for (int ch = 0; ch < NA_; ch += 256) {
    const int j = ch + tid;
    const bool m = (node_idx[nbase + j] == d);
    const unsigned long long wm = __ballot(m);
    if (lane == 0) masks[wv] = wm;
    __syncthreads();
    int before = 0, tot = 0;
#pragma unroll
    for (int w = 0; w < 4; w++) {
      const unsigned long long mk = masks[w];
      const int pc = __popcll(mk);
      tot += pc;
      if (w < wv) before += pc;
    }
    before += __popcll(wm & ((1ull << lane) - 1ull));
    if (m) mbuf[before] = j;
    __syncthreads();
    for (int k = 0; k < tot; k++) {
      const int i = mbuf[k];
      const float4 v = *(const float4*)(x + ((size_t)bz * N_ + a_idx[i]) * C_ + c0);
      acc.x += v.x; acc.y += v.y; acc.z += v.z; acc.w += v.w;
    }
    total_cnt += tot;
    __syncthreads();   // protect masks/mbuf before next chunk
  }
  const float s = 1.0f + (float)total_cnt;
  const float f[4] = {acc.x / s, acc.y / s, acc.z / s, acc.w / s};
  unsigned h4[4], l4[4];
#pragma unroll
  for (int j = 0; j < 4; j++) {
    h4[j] = f2bf_rtne(f[j]);
    const float fh = __uint_as_float(h4[j] << 16);
    l4[j] = f2bf_rtne(f[j] - fh);
  }
  uint2 ph, pl;
  ph.x = h4[0] | (h4[1] << 16); ph.y = h4[2] | (h4[3] << 16);
  pl.x = l4[0] | (l4[1] << 16); pl.y = l4[2] | (l4[3] << 16);
  const size_t o = (size_t)blk * C_ + c0;
  *(uint2*)&xmh[o] = ph;
  *(uint2*)&xml[o] = pl;
}

// ---------------------------------------------------------------------------
// K10: qkv GEMM via bf16x3 MFMA, software-pipelined.
// Epilogue writes Q(x0.125)/K [b,h,t,d] and V transposed [b,h,d,t], all hi/lo.
// ---------------------------------------------------------------------------
__global__ __launch_bounds__(256) void k_qkv_mfma(
    const unsigned short* __restrict__ xmh, const unsigned short* __restrict__ xml,
    const unsigned short* __restrict__ wqh, const unsigned short* __restrict__ wql,
    unsigned short* __restrict__ gqh, unsigned short* __restrict__ gql,
    unsigned short* __restrict__ gkh, unsigned short* __restrict__ gkl,
    unsigned short* __restrict__ gvh, unsigned short* __restrict__ gvl) {
  __shared__ __align__(16) unsigned short Ahs[128][40], Als[128][40];
  __shared__ __align__(16) unsigned short Bhs[128][40], Bls[128][40];
  const int nb = blockIdx.x;   // 24
  const int mb = blockIdx.y;   // 32
  const int tid = threadIdx.x;
  const int lane = tid & 63, wv = tid >> 6;
  const int wr = wv >> 1, wc = wv & 1;
  const int fr = lane & 15, fg = lane >> 4;
  const int srow = tid >> 1, scol = (tid & 1) * 16;
  const size_t abase = (size_t)(mb * 128 + srow) * C_ + scol;
  const size_t bbase = (size_t)(nb * 128 + srow) * C_ + scol;
  uint4 rah0 = *(const uint4*)(xmh + abase),    rah1 = *(const uint4*)(xmh + abase + 8);
  uint4 ral0 = *(const uint4*)(xml + abase),    ral1 = *(const uint4*)(xml + abase + 8);
  uint4 rbh0 = *(const uint4*)(wqh + bbase),    rbh1 = *(const uint4*)(wqh + bbase + 8);
  uint4 rbl0 = *(const uint4*)(wql + bbase),    rbl1 = *(const uint4*)(wql + bbase + 8);
  f32x4 acc[4][4] = {};
  for (int k0 = 0; k0 < C_; k0 += 32) {
    __syncthreads();
    *(uint4*)&Ahs[srow][scol]     = rah0;  *(uint4*)&Ahs[srow][scol + 8] = rah1;
    *(uint4*)&Als[srow][scol]     = ral0;  *(uint4*)&Als[srow][scol + 8] = ral1;
    *(uint4*)&Bhs[srow][scol]     = rbh0;  *(uint4*)&Bhs[srow][scol + 8] = rbh1;
    *(uint4*)&Bls[srow][scol]     = rbl0;  *(uint4*)&Bls[srow][scol + 8] = rbl1;
    if (k0 + 32 < C_) {
      const int kn = k0 + 32;
      rah0 = *(const uint4*)(xmh + abase + kn); rah1 = *(const uint4*)(xmh + abase + kn + 8);
      ral0 = *(const uint4*)(xml + abase + kn); ral1 = *(const uint4*)(xml + abase + kn + 8);
      rbh0 = *(const uint4*)(wqh + bbase + kn); rbh1 = *(const uint4*)(wqh + bbase + kn + 8);
      rbl0 = *(const uint4*)(wql + bbase + kn); rbl1 = *(const uint4*)(wql + bbase + kn + 8);
    }
    __syncthreads();
    short8v bh[4], bl[4];
#pragma unroll
    for (int j = 0; j < 4; j++) {
      bh[j] = *(const short8v*)&Bhs[wc * 64 + j * 16 + fr][fg * 8];
      bl[j] = *(const short8v*)&Bls[wc * 64 + j * 16 + fr][fg * 8];
    }
#pragma unroll
    for (int i = 0; i < 4; i++) {
      const short8v ah = *(const short8v*)&Ahs[wr * 64 + i * 16 + fr][fg * 8];
      const short8v al = *(const short8v*)&Als[wr * 64 + i * 16 + fr][fg * 8];
#pragma unroll
      for (int j = 0; j < 4; j++) {
        acc[i][j] = __builtin_amdgcn_mfma_f32_16x16x32_bf16(al, bh[j], acc[i][j], 0, 0, 0);
        acc[i][j] = __builtin_amdgcn_mfma_f32_16x16x32_bf16(ah, bl[j], acc[i][j], 0, 0, 0);
        acc[i][j] = __builtin_amdgcn_mfma_f32_16x16x32_bf16(ah, bh[j], acc[i][j], 0, 0, 0);
      }
    }
  }
  // D layout: col(n within 16) = fr, row(m within 16) = fg*4 + r.
  const int nq = nb * 2 + wc;          // n>>6: 0..47
  const int w = nq >> 4, h = nq & 15;  // tensor / head
  const int bb = mb >> 3;              // batch
  const int tb = (mb & 7) * 128 + wr * 64;
  const size_t base = (size_t)(bb * 16 + h) * 65536;
  if (w < 2) {
    unsigned short* __restrict__ dh = (w == 0) ? gqh : gkh;
    unsigned short* __restrict__ dl = (w == 0) ? gql : gkl;
    const float sc = (w == 0) ? 0.125f : 1.0f;
#pragma unroll
    for (int i = 0; i < 4; i++)
#pragma unroll
      for (int j = 0; j < 4; j++) {
        const int dc = j * 16 + fr;
#pragma unroll
        for (int r = 0; r < 4; r++) {
          const int t = tb + i * 16 + fg * 4 + r;
          const float f = acc[i][j][r] * sc;
          const unsigned short hv = f2bf_rtne(f);
          const float fh = __uint_as_float((unsigned)hv << 16);
          const unsigned short lv = f2bf_rtne(f - fh);
          dh[base + (size_t)t * 64 + dc] = hv;
          dl[base + (size_t)t * 64 + dc] = lv;
        }
      }
  } else {
#pragma unroll
    for (int i = 0; i < 4; i++)
#pragma unroll
      for (int j = 0; j < 4; j++) {
        const int dc = j * 16 + fr;
        const int t0 = tb + i * 16 + fg * 4;
        unsigned hv[4], lv[4];
#pragma unroll
        for (int r = 0; r < 4; r++) {
          const float f = acc[i][j][r];
          hv[r] = f2bf_rtne(f);
          const float fh = __uint_as_float(hv[r] << 16);
          lv[r] = f2bf_rtne(f - fh);
        }
        uint2 ph, pl;
        ph.x = hv[0] | (hv[1] << 16); ph.y = hv[2] | (hv[3] << 16);
        pl.x = lv[0] | (lv[1] << 16); pl.y = lv[2] | (lv[3] << 16);
        *(uint2*)&gvh[base + (size_t)dc * 1024 + t0] = ph;
        *(uint2*)&gvl[base + (size_t)dc * 1024 + t0] = pl;
      }
  }
}

// ---------------------------------------------------------------------------
// K11: flash attention via bf16x3 MFMA (verified R4/R5).
// ---------------------------------------------------------------------------
__global__ __launch_bounds__(256, 3) void k_attn(
    const unsigned short* __restrict__ gqh, const unsigned short* __restrict__ gql,
    const unsigned short* __restrict__ gkh, const unsigned short* __restrict__ gkl,
    const unsigned short* __restrict__ gvh, const unsigned short* __restrict__ gvl,
    unsigned short* __restrict__ omh, unsigned short* __restrict__ oml) {
  __shared__ __align__(16) unsigned short Qh[64][64], Ql[64][64];
  __shared__ __align__(16) unsigned short KP[2][64][72];   // K hi/lo, then P fp32
  __shared__ __align__(16) unsigned short VTh[64][72], VTl[64][72];
  float* const Pf = (float*)&KP[0][0][0];                  // [64][68] fp32 view
  const int qb = blockIdx.x, h = blockIdx.y, bz = blockIdx.z;
  const int tid = threadIdx.x;
  const int lane = tid & 63, wv = tid >> 6;
  const int fr = lane & 15, fg = lane >> 4;
  const int lr = tid >> 2, lc = (tid & 3) * 16;
  const size_t hb = (size_t)(bz * 16 + h) * 65536;
  { // stage Q (already scaled by 0.125 in k_qkv), XOR-swizzled
    const size_t o0 = hb + (size_t)(qb * 64 + lr) * 64 + lc;
    const int sw = lr & 7, kb0 = lc >> 3;
    *(uint4*)&Qh[lr][((kb0 + 0) ^ sw) * 8] = *(const uint4*)(gqh + o0);
    *(uint4*)&Qh[lr][((kb0 + 1) ^ sw) * 8] = *(const uint4*)(gqh + o0 + 8);
    *(uint4*)&Ql[lr][((kb0 + 0) ^ sw) * 8] = *(const uint4*)(gql + o0);
    *(uint4*)&Ql[lr][((kb0 + 1) ^ sw) * 8] = *(const uint4*)(gql + o0 + 8);
  }
  f32x4 o_[4] = {};
  float m_r[4] = {-INFINITY, -INFINITY, -INFINITY, -INFINITY};
  float l_r[4] = {0.0f, 0.0f, 0.0f, 0.0f};
  float alpha[4];
  for (int kt = 0; kt < 16; kt++) {
    __syncthreads();          // prev PV reads of KP(P)/VT done
    { // stage K rows + VT rows (pure coalesced copies, V pre-transposed)
      const size_t ko = hb + (size_t)(kt * 64 + lr) * 64 + lc;
      *(uint4*)&KP[0][lr][lc]     = *(const uint4*)(gkh + ko);
      *(uint4*)&KP[0][lr][lc + 8] = *(const uint4*)(gkh + ko + 8);
      *(uint4*)&KP[1][lr][lc]     = *(const uint4*)(gkl + ko);
      *(uint4*)&KP[1][lr][lc + 8] = *(const uint4*)(gkl + ko + 8);
      const size_t vo = hb + (size_t)lr * 1024 + kt * 64 + lc;
      *(uint4*)&VTh[lr][lc]     = *(const uint4*)(gvh + vo);
      *(uint4*)&VTh[lr][lc + 8] = *(const uint4*)(gvh + vo + 8);
      *(uint4*)&VTl[lr][lc]     = *(const uint4*)(gvl + vo);
      *(uint4*)&VTl[lr][lc + 8] = *(const uint4*)(gvl + vo + 8);
    }
    __syncthreads();          // staging visible
    // QK^T: S[q][k] = Q . K (both row-frags -> D = A*B^T), bf16x3
    f32x4 sacc[4] = {};
#pragma unroll
    for (int ks = 0; ks < 2; ks++) {
      const int kb = ks * 4 + fg;
      const short8v qh_ = *(const short8v*)&Qh[wv * 16 + fr][(kb ^ (fr & 7)) * 8];
      const short8v ql_ = *(const short8v*)&Ql[wv * 16 + fr][(kb ^ (fr & 7)) * 8];
#pragma unroll
      for (int nn = 0; nn < 4; nn++) {
        const short8v kh_ = *(const short8v*)&KP[0][nn * 16 + fr][ks * 32 + fg * 8];
        const short8v kl_ = *(const short8v*)&KP[1][nn * 16 + fr][ks * 32 + fg * 8];
        sacc[nn] = __builtin_amdgcn_mfma_f32_16x16x32_bf16(ql_, kh_, sacc[nn], 0, 0, 0);
        sacc[nn] = __builtin_amdgcn_mfma_f32_16x16x32_bf16(qh_, kl_, sacc[nn], 0, 0, 0);
        sacc[nn] = __builtin_amdgcn_mfma_f32_16x16x32_bf16(qh_, kh_, sacc[nn], 0, 0, 0);
      }
    }
    // online softmax (rows = fg*4 + r, cols spread over 16 lanes x 4 nn)
#pragma unroll
    for (int r = 0; r < 4; r++) {
      float tmax = fmaxf(fmaxf(sacc[0][r], sacc[1][r]), fmaxf(sacc[2][r], sacc[3][r]));
#pragma unroll
      for (int off = 8; off; off >>= 1) tmax = fmaxf(tmax, __shfl_xor(tmax, off, 16));
      const float mn = fmaxf(m_r[r], tmax);
      alpha[r] = expf(m_r[r] - mn);
      float s_ = 0.0f;
#pragma unroll
      for (int nn = 0; nn < 4; nn++) { sacc[nn][r] = expf(sacc[nn][r] - mn); s_ += sacc[nn][r]; }
#pragma unroll
      for (int off = 8; off; off >>= 1) s_ += __shfl_xor(s_, off, 16);
      m_r[r] = mn;
      l_r[r] = l_r[r] * alpha[r] + s_;
    }
    __syncthreads();          // all K-frag reads done -> overwrite region as P
#pragma unroll
    for (int nn = 0; nn < 4; nn++)
#pragma unroll
      for (int r = 0; r < 4; r++)
        Pf[(wv * 16 + fg * 4 + r) * 68 + nn * 16 + fr] = sacc[nn][r];
    __syncthreads();          // P visible (cross-lane)
#pragma unroll
    for (int nd = 0; nd < 4; nd++)
#pragma unroll
      for (int r = 0; r < 4; r++) o_[nd][r] *= alpha[r];
    // PV: O[q][d] = P . V = A(P rows) * B(VT rows)^T, bf16x3
#pragma unroll
    for (int ks = 0; ks < 2; ks++) {
      float pf[8];
      *(float4*)&pf[0] = *(const float4*)&Pf[(wv * 16 + fr) * 68 + ks * 32 + fg * 8];
      *(float4*)&pf[4] = *(const float4*)&Pf[(wv * 16 + fr) * 68 + ks * 32 + fg * 8 + 4];
      short8v ph_, pl_;
      split8(pf, ph_, pl_);
#pragma unroll
      for (int nd = 0; nd < 4; nd++) {
        const short8v vh_ = *(const short8v*)&VTh[nd * 16 + fr][ks * 32 + fg * 8];
        const short8v vl_ = *(const short8v*)&VTl[nd * 16 + fr][ks * 32 + fg * 8];
        o_[nd] = __builtin_amdgcn_mfma_f32_16x16x32_bf16(pl_, vh_, o_[nd], 0, 0, 0);
        o_[nd] = __builtin_amdgcn_mfma_f32_16x16x32_bf16(ph_, vl_, o_[nd], 0, 0, 0);
        o_[nd] = __builtin_amdgcn_mfma_f32_16x16x32_bf16(ph_, vh_, o_[nd], 0, 0, 0);
      }
    }
  }
  // epilogue: bf16 hi/lo om for MFMA proj. col = fr (d in 16-block), row = fg*4+r.
#pragma unroll
  for (int r = 0; r < 4; r++) {
    const float inv = 1.0f / l_r[r];
    const int t = qb * 64 + wv * 16 + fg * 4 + r;
    const size_t ob = (size_t)(bz * ND_ + t) * C_ + h * 64;
#pragma unroll
    for (int nd = 0; nd < 4; nd++) {
      const float f = o_[nd][r] * inv;
      const unsigned short hv = f2bf_rtne(f);
      const float fh = __uint_as_float((unsigned)hv << 16);
      const unsigned short lv = f2bf_rtne(f - fh);
      omh[ob + nd * 16 + fr] = hv;
      oml[ob + nd * 16 + fr] = lv;
    }
  }
}

// ---------------------------------------------------------------------------
// K12: proj GEMM via bf16x3 MFMA, software-pipelined. ym = om@Wp^T + bp
// ---------------------------------------------------------------------------
__global__ __launch_bounds__(256) void k_proj_mfma(
    const unsigned short* __restrict__ omh, const unsigned short* __restrict__ oml,
    const unsigned short* __restrict__ wph, const unsigned short* __restrict__ wpl,
    const float* __restrict__ bp, float* __restrict__ ym) {
  __shared__ __align__(16) unsigned short Ahs[128][40], Als[128][40];
  __shared__ __align__(16) unsigned short Bhs[128][40], Bls[128][40];
  const int nb = blockIdx.x;   // 8
  const int mb = blockIdx.y;   // 32
  const int tid = threadIdx.x;
  const int lane = tid & 63, wv = tid >> 6;
  const int wr = wv >> 1, wc = wv & 1;
  const int fr = lane & 15, fg = lane >> 4;
  const int srow = tid >> 1, scol = (tid & 1) * 16;
  const size_t abase = (size_t)(mb * 128 + srow) * C_ + scol;
  const size_t bbase = (size_t)(nb * 128 + srow) * C_ + scol;
  uint4 rah0 = *(const uint4*)(omh + abase),    rah1 = *(const uint4*)(omh + abase + 8);
  uint4 ral0 = *(const uint4*)(oml + abase),    ral1 = *(const uint4*)(oml + abase + 8);
  uint4 rbh0 = *(const uint4*)(wph + bbase),    rbh1 = *(const uint4*)(wph + bbase + 8);
  uint4 rbl0 = *(const uint4*)(wpl + bbase),    rbl1 = *(const uint4*)(wpl + bbase + 8);
  f32x4 acc[4][4] = {};
  for (int k0 = 0; k0 < C_; k0 += 32) {
    __syncthreads();
    *(uint4*)&Ahs[srow][scol]     = rah0;  *(uint4*)&Ahs[srow][scol + 8] = rah1;
    *(uint4*)&Als[srow][scol]     = ral0;  *(uint4*)&Als[srow][scol + 8] = ral1;
    *(uint4*)&Bhs[srow][scol]     = rbh0;  *(uint4*)&Bhs[srow][scol + 8] = rbh1;
    *(uint4*)&Bls[srow][scol]     = rbl0;  *(uint4*)&Bls[srow][scol + 8] = rbl1;
    if (k0 + 32 < C_) {
      const int kn = k0 + 32;
      rah0 = *(const uint4*)(omh + abase + kn); rah1 = *(const uint4*)(omh + abase + kn + 8);
      ral0 = *(const uint4*)(oml + abase + kn); ral1 = *(const uint4*)(oml + abase + kn + 8);
      rbh0 = *(const uint4*)(wph + bbase + kn); rbh1 = *(const uint4*)(wph + bbase + kn + 8);
      rbl0 = *(const uint4*)(wpl + bbase + kn); rbl1 = *(const uint4*)(wpl + bbase + kn + 8);
    }
    __syncthreads();
    short8v bh[4], bl[4];
#pragma unroll
    for (int j = 0; j < 4; j++) {
      bh[j] = *(const short8v*)&Bhs[wc * 64 + j * 16 + fr][fg * 8];
      bl[j] = *(const short8v*)&Bls[wc * 64 + j * 16 + fr][fg * 8];
    }
#pragma unroll
    for (int i = 0; i < 4; i++) {
      const short8v ah = *(const short8v*)&Ahs[wr * 64 + i * 16 + fr][fg * 8];
      const short8v al = *(const short8v*)&Als[wr * 64 + i * 16 + fr][fg * 8];
#pragma unroll
      for (int j = 0; j < 4; j++) {
        acc[i][j] = __builtin_amdgcn_mfma_f32_16x16x32_bf16(al, bh[j], acc[i][j], 0, 0, 0);
        acc[i][j] = __builtin_amdgcn_mfma_f32_16x16x32_bf16(ah, bl[j], acc[i][j], 0, 0, 0);
        acc[i][j] = __builtin_amdgcn_mfma_f32_16x16x32_bf16(ah, bh[j], acc[i][j], 0, 0, 0);
      }
    }
  }
#pragma unroll
  for (int j = 0; j < 4; j++) {
    const int n = nb * 128 + wc * 64 + j * 16 + fr;
    const float bias = bp[n];
#pragma unroll
    for (int i = 0; i < 4; i++)
#pragma unroll
      for (int r = 0; r < 4; r++) {
        const int m = mb * 128 + wr * 64 + i * 16 + fg * 4 + r;
        ym[(size_t)m * C_ + n] = acc[i][j][r] + bias;
      }
  }
}

// K13: scatter merged rows back to all 4096 tokens
__global__ __launch_bounds__(256) void k_unmerge(const float* __restrict__ ym,
                                                 const int* __restrict__ rowmap,
                                                 float* __restrict__ out) {
  const int blk = blockIdx.x;                 // B_*N_
  const int bz = blk >> 12;
  const int r = rowmap[blk];
  const float4* src = (const float4*)(ym + ((size_t)bz * ND_ + r) * C_);
  float4* dst = (float4*)(out + (size_t)blk * C_);
  dst[threadIdx.x] = src[threadIdx.x];
}

// ---------------------------------------------------------------------------
extern "C" void kernel_launch(void* const* d_in, const int* in_sizes, int n_in,
                              void* d_out, int out_size, void* d_ws, size_t ws_size,
                              hipStream_t stream) {
  const float* x    = (const float*)d_in[0];
  const float* Wqkv = (const float*)d_in[1];
  const float* Wp   = (const float*)d_in[2];
  const float* bp   = (const float*)d_in[3];
  char* ws = (char*)d_ws;
  double* dinv    = (double*)(ws + 0);          //  131072 B
  int*   b_idx    = (int*)(ws + 131072);
  int*   a_idx    = (int*)(ws + 135168);
  int*   node_idx = (int*)(ws + 147456);
  int*   rowmap   = (int*)(ws + 212992);
  int*   flaglist = (int*)(ws + 278528);        // 49152 B (<= B_*NA_ ids)
  float* pv1      = (float*)(ws + 327680);      // 393216 B used (8 tiles)
  int*   nflag    = (int*)(ws + 720896);        // 4 B, in pv1's unused tail
  int*   pi1      = (int*)(ws + 1114112);
  float* pv2      = (float*)(ws + 1900544);
  int*   pi2      = (int*)(ws + 2686976);
  // Lifetime-disjoint aliased regions (all hand-checked, stream-ordered):
  // [3,473,408 .. 70,582,272): xh/xl (prep->scores)
  unsigned short* xh = (unsigned short*)(ws + 3473408);    // 33,554,432 B
  unsigned short* xl = (unsigned short*)(ws + 37027840);   // 33,554,432 B
  // xmh/xml (merge_fused->qkv) alias xh tail
  unsigned short* xmh = (unsigned short*)(ws + 20250624);  // 8,388,608 B
  unsigned short* xml = (unsigned short*)(ws + 28639232);  // 8,388,608 B
  // Wq hi/lo (prep_w->qkv) alias xl head
  unsigned short* wqh = (unsigned short*)(ws + 37027840);  // 6,291,456 B
  unsigned short* wql = (unsigned short*)(ws + 43319296);  // 6,291,456 B
  // Q/K/V hi-lo (qkv->attn): Q aliases dead xh head; K/V in fresh region
  unsigned short* gqh = (unsigned short*)(ws + 3473408);   // 8,388,608 B
  unsigned short* gql = (unsigned short*)(ws + 11862016);  // 8,388,608 B
  unsigned short* gkh = (unsigned short*)(ws + 49610752);  // 8,388,608 B
  unsigned short* gkl = (unsigned short*)(ws + 57999360);  // 8,388,608 B
  unsigned short* gvh = (unsigned short*)(ws + 66387968);  // 8,388,608 B
  unsigned short* gvl = (unsigned short*)(ws + 74776576);  // 8,388,608 B  (ends 83,165,184)
  // Wp hi/lo (prep_w->proj), tail region
  unsigned short* wph = (unsigned short*)(ws + 83165184);  // 2,097,152 B
  unsigned short* wpl = (unsigned short*)(ws + 85262336);  // 2,097,152 B  (ends 87,359,488)
  // om hi/lo (attn->proj) alias dead xmh/xml
  unsigned short* omh = (unsigned short*)(ws + 20250624);  // 8,388,608 B
  unsigned short* oml = (unsigned short*)(ws + 28639232);  // 8,388,608 B
  // ym fp32 (proj->unmerge) aliases dead gqh/gql
  float* ym = (float*)(ws + 3473408);                      // 16,777,216 B
  float* out = (float*)d_out;

  hipMemsetAsync(nflag, 0, sizeof(int), stream);
  k_init_indices<<<1, 1024, 0, stream>>>(b_idx, a_idx);
  k_row_norms<<<B_ * N_, 256, 0, stream>>>(x, dinv);
  k_prep<<<B_ * N_, 256, 0, stream>>>(x, dinv, xh, xl);
  k_scores_mfma<<<dim3(8, 24, B_), 256, 0, stream>>>(xh, xl, a_idx, b_idx, pv1, pi1, pv2, pi2);
  k_prep_w<<<4096, 256, 0, stream>>>(Wqkv, Wp, wqh, wql, wph, wpl);  // after scores (xl dead)
  k_finalize<<<(B_ * NA_) / 256, 256, 0, stream>>>(pv1, pi1, pv2, pi2, node_idx, flaglist, nflag);
  k_recheck<<<1536, 256, 0, stream>>>(x, dinv, a_idx, b_idx, pv1, pi1, pv2, pi2,
                                      flaglist, nflag, node_idx);
  k_rowmap<<<(B_ * N_) / 256, 256, 0, stream>>>(a_idx, b_idx, node_idx, rowmap);
  k_merge_fused<<<B_ * ND_, 256, 0, stream>>>(x, a_idx, b_idx, node_idx, xmh, xml);
  k_qkv_mfma<<<dim3(24, 32), 256, 0, stream>>>(xmh, xml, wqh, wql,
                                               gqh, gql, gkh, gkl, gvh, gvl);
  k_attn<<<dim3(16, 16, B_), 256, 0, stream>>>(gqh, gql, gkh, gkl, gvh, gvl, omh, oml);
  k_proj_mfma<<<dim3(8, 32), 256, 0, stream>>>(omh, oml, wph, wpl, bp, ym);
  k_unmerge<<<B_ * N_, 256, 0, stream>>>(ym, rowmap, out);
}